// Round 15
// baseline (248.880 us; speedup 1.0000x reference)
//
#include <hip/hip_runtime.h>
#include <stdint.h>

static constexpr int kN = 128;
static constexpr int kTri = (kN * (kN - 1)) / 2;   // 8128 (BT scratch indexing)
static constexpr int kTriD = (kN * (kN + 1)) / 2;  // 8256 cells incl. diagonal
static constexpr int kThreads = 1024;              // 16 waves: 4/SIMD TLP required (R8/R10)
static constexpr float kNeg = -9999.0f;
static constexpr float kThresh = -9000.0f;
static constexpr float kArcBonus = 5.0f;
static constexpr int kDynLds = kTriD * 16;  // 132,096 B (one float4 quad per cell)
static constexpr int kCMax = 9;             // max row-cache slots per lane
static constexpr int kSer = 24;             // barrier-free serial region: k = 1..24 (R12; 28/32 spill)
static constexpr int kStride = 40;          // serial row stride (primaries lam < 40)
static constexpr int kTail = 112;           // barrier-free single-wave tail: k >= 112

__device__ __forceinline__ int rowBase(int i) { return (i * (2 * kN - 1 - i)) / 2; }
__device__ __forceinline__ int colBaseD(int c) { return (c * (c + 1)) / 2; }  // cells (r<=c, c)

// LDS-only workgroup barrier: orders LDS without draining vmcnt (wsBT stores
// and vL/vR prefetch loads stay in flight across steps).
__device__ __forceinline__ void ldsBarrier() {
    asm volatile("s_waitcnt lgkmcnt(0)\n\ts_barrier" ::: "memory");
}

// DPP cross-lane reduce helpers -- pure VALU, never touch the LDS pipe.
// 0xB1 xor1, 0x4E xor2, 0x141 half-mirror (8 lanes), 0x140 row-mirror (16).
template <int CTRL>
__device__ __forceinline__ float dppMax(float x) {
    const int y = __builtin_amdgcn_update_dpp(__float_as_int(x), __float_as_int(x),
                                              CTRL, 0xF, 0xF, true);
    return fmaxf(x, __int_as_float(y));
}
template <int CTRL>
__device__ __forceinline__ int dppMinI(int x) {
    const int y = __builtin_amdgcn_update_dpp(x, x, CTRL, 0xF, 0xF, true);
    return (y < x) ? y : x;
}
template <int P>
__device__ __forceinline__ float grpMax(float x) {
    float r = dppMax<0xB1>(x);
    if constexpr (P >= 4) r = dppMax<0x4E>(r);
    if constexpr (P >= 8) r = dppMax<0x141>(r);
    if constexpr (P >= 16) r = dppMax<0x140>(r);
    return r;
}
template <int P>
__device__ __forceinline__ int grpMinI(int x) {
    int r = dppMinI<0xB1>(x);
    if constexpr (P >= 4) r = dppMinI<0x4E>(r);
    if constexpr (P >= 8) r = dppMinI<0x141>(r);
    if constexpr (P >= 16) r = dppMinI<0x140>(r);
    return r;
}

// Quad per cell: {x=s00, y=s11, z=s01, w=s10}, col-major incl. diagonal (diag=0).
__device__ __forceinline__ float4 writeCell(float4* __restrict__ Q4,
                                            uint32_t* __restrict__ wsBT,
                                            int qjb, int i, int wsIdx, int k,
                                            float gb, int ib, float vLc, float vRc,
                                            float v01, int i01, float v11, int i11) {
    const float v00 = (gb + vLc) + kArcBonus;
    const float v10 = (gb + vRc) + kArcBonus;
    const float new10 = (v10 > kThresh) ? v10 : kNeg;
    if (new10 > v11) { v11 = new10; i11 = k; }  // q=j candidate; strict > keeps earlier q
    float4 w = make_float4(kNeg, kNeg, kNeg, kNeg);
    uint32_t p = 0;
    if (v00 > kThresh) { w.x = v00; p |= (uint32_t)(i + ib); }
    if (v01 > kThresh) { w.z = v01; p |= (uint32_t)(i + i01) << 8; }
    if (v10 > kThresh) { w.w = v10; p |= (uint32_t)(i + ib) << 16; }
    if (v11 > kThresh) { w.y = v11; p |= (uint32_t)(i + i11) << 24; }
    Q4[qjb + i] = w;      // one ds_write_b128
    wsBT[wsIdx] = p;      // lone global store; drained at the final __syncthreads
    return w;
}

// ---- Barrier-free serial region (k = 1..kSer), verified R12 ----
// Waves 0..3 own rows r = kStride*w + lane.  A lane runs step k only while
// lam + k <= 63; then every dependency was written by a lane of the SAME
// wave at an earlier step (lam_q + width = lam + k <= 63).  Per-wave
// in-order LDS => visible without barriers.  Overlap rows (lam >= kStride)
// are bitwise-identical duplicates => benign same-value writes.
__device__ __forceinline__ void doStepSerialNB(int k, int lam, int i,
                                               float4* __restrict__ Q4,
                                               uint32_t* __restrict__ wsBT,
                                               int& j, int& qjb, int rbi,
                                               const float*& pL, const float*& pR,
                                               float& vL, float& vR,
                                               float (&sr11)[kSer + 1], float (&sr01)[kSer + 1],
                                               float (&sr10)[kSer + 1]) {
    const bool act = (lam + k <= 63) && (i < kN - k);
    const float vLc = vL, vRc = vR;
    const int qjbc = qjb;
    float bmax = -3.0e38f, v01 = -3.0e38f, v11 = -3.0e38f;
    int ib = 0, i01 = 0, i11 = 0x7FFFFFFF;
    if (act) {
        float4 cur = Q4[qjbc + i + 1];  // quad(i+1, j); diagonal zeros when k==1
        bmax = cur.z; ib = 0;           // base(0) = 0 + s01[i+1][j]
        const float p00 = (cur.z + vLc) + kArcBonus;
        v01 = (p00 > kThresh) ? p00 : kNeg; i01 = 0;  // part00 seed
#pragma unroll
        for (int m = 1; m < kSer; ++m) {
            if (m < k) {  // compile-time when k is constant-folded
                const float4 nxt = Q4[qjbc + i + m + 1];  // quad(q+1, j)
                const float base = sr11[m] + nxt.z;       // s11[i][q] + s01[q+1][j]
                const float p01v = sr01[m] + cur.x;       // s01[i][q] + s00[q][j]
                const float p11v = sr10[m] + cur.y;       // s10[i][q] + s11[q][j]
                if (base > bmax) { bmax = base; ib = m; }  // strict > keeps earliest m
                if (p01v > v01) { v01 = p01v; i01 = m; }
                if (p11v > v11) { v11 = p11v; i11 = m; }
                cur = nxt;
            }
        }
    }
    // Incremental prefetch of next step's operands (overlaps write).
    if (k < kSer) {
        const bool nact = (lam + k + 1 <= 63) && (i < kN - (k + 1));
        qjb += j + 1; ++j; pL += kN; ++pR;
        vL = nact ? *pL : 0.f;
        vR = nact ? *pR : 0.f;
    }
    if (act) {
        const float4 w = writeCell(Q4, wsBT, qjbc, i, rbi + k - 1, k,
                                   bmax, ib, vLc, vRc, v01, i01, v11, i11);
        sr11[k] = w.y; sr01[k] = w.z; sr10[k] = w.w;  // constant index (k unrolled)
    }
}

// ---- Chunked phases: register row-cache + fw forwarding (R7/R12, verified) ----
template <int LP, int C>
__device__ __forceinline__ void preloadRow(int k0, int tid,
                                           const float4* __restrict__ Q4,
                                           float (&r11)[kCMax], float (&r01)[kCMax],
                                           float (&r10)[kCMax]) {
    const int i = tid >> LP;
    const int l = tid & ((1 << LP) - 1);
    const int mlo = l * C;
    const int mstart = mlo ? mlo : 1;
    const bool act = i < (kN - k0);
#pragma unroll
    for (int c = 0; c < C; ++c) {
        const int m = mstart + c;
        if (act && (m < mlo + C) && (m <= k0 - 1)) {
            const float4 d = Q4[colBaseD(i + m) + i];  // quad(i, i+m), immutable
            r11[c] = d.y; r01[c] = d.z; r10[c] = d.w;
        }
    }
    // Slots with m > k0-1 stay stale: first read at step k=m+1 substitutes fw.
}

template <int LP, int C>
__device__ __forceinline__ void fwInit(int k0, int tid,
                                       const float (&r11)[kCMax], const float (&r01)[kCMax],
                                       const float (&r10)[kCMax],
                                       float& fw11, float& fw01, float& fw10) {
    const int l = tid & ((1 << LP) - 1);
    const int mlo = l * C;
    const int mstart = mlo ? mlo : 1;
#pragma unroll
    for (int c = 0; c < C; ++c) {
        if (mstart + c == k0 - 1) { fw11 = r11[c]; fw01 = r01[c]; fw10 = r10[c]; }
    }
}

template <int LP, int C>
__device__ __forceinline__ void doStepC(int k, int i, int l,
                                        float4* __restrict__ Q4,
                                        uint32_t* __restrict__ wsBT,
                                        int& j, int& qjb, int rbi,
                                        const float*& pL, const float*& pR,
                                        float& vL, float& vR,
                                        float (&r11)[kCMax], float (&r01)[kCMax],
                                        float (&r10)[kCMax],
                                        float& fw11, float& fw01, float& fw10) {
    constexpr int P = 1 << LP;
    static_assert(P <= 16, "reductions must stay pure-DPP");
    const bool act = i < kN - k;
    const float vLc = vL, vRc = vR;  // prefetch below overwrites vL/vR
    const int mlo = l * C;
    const int mstart = mlo ? mlo : 1;
    const int mhi = (mlo + C < k) ? (mlo + C) : k;
    const int qjbc = qjb;

    float bmax = -3.0e38f, v01 = -3.0e38f, v11 = -3.0e38f;
    int ib = 0x7FFFFFFF, i01 = 0x7FFFFFFF, i11 = 0x7FFFFFFF;

    const int mf = k - 1;
    const bool lact = act && (mstart < mhi);
    float4 cur = make_float4(0.f, 0.f, 0.f, 0.f);
    if (lact) cur = Q4[qjbc + i + mstart];  // column seed quad(i+mstart, j)
    if (act && mlo == 0) {
        bmax = cur.z; ib = 0;  // base(0) = 0 + s01[i+1][j]
        const float p00 = (cur.z + vLc) + kArcBonus;
        v01 = (p00 > kThresh) ? p00 : kNeg; i01 = 0;  // part00 seed
    }
#pragma unroll
    for (int c = 0; c < C; ++c) {
        const int m = mstart + c;
        // Row operands: registers; fresh slot m==k-1 comes from fw (the cell
        // this group computed last step), committed into the cache here.
        const bool isF = (m == mf);
        const float a11 = isF ? fw11 : r11[c];
        const float a01 = isF ? fw01 : r01[c];
        const float a10 = isF ? fw10 : r10[c];
        r11[c] = a11; r01[c] = a01; r10[c] = a10;
        const bool on = lact && (m < mhi);
        if (on) {
            const float4 nxt = Q4[qjbc + i + m + 1];  // quad(q+1, j); imm offset
            const float base = a11 + nxt.z;           // s11[i][q] + s01[q+1][j]
            const float p01v = a01 + cur.x;           // s01[i][q] + s00[q][j]
            const float p11v = a10 + cur.y;           // s10[i][q] + s11[q][j]
            if (base > bmax) { bmax = base; ib = m; }  // strict > keeps earliest m
            if (p01v > v01) { v01 = p01v; i01 = m; }
            if (p11v > v11) { v11 = p11v; i11 = m; }
            cur = nxt;
        }
    }

    // Incremental prefetch of next step's operands (overlaps reduction+barrier).
    {
        const bool nact = i < kN - (k + 1);
        qjb += j + 1; ++j; pL += kN; ++pR;
        vL = nact ? *pL : 0.f;
        vR = nact ? *pR : 0.f;
    }

    // Value butterfly (pure DPP, VALU pipe only): log2(P) levels.
    const float gB = grpMax<P>(bmax);
    const float g01 = grpMax<P>(v01);
    const float g11 = grpMax<P>(v11);
    // Earliest-m argmax: mask losers to INT_MAX, min-butterfly (pure DPP).
    int cB = (bmax == gB) ? ib : 0x7FFFFFFF;
    int c01 = (v01 == g01) ? i01 : 0x7FFFFFFF;
    int c11 = (v11 == g11) ? i11 : 0x7FFFFFFF;
    cB = grpMinI<P>(cB);
    c01 = grpMinI<P>(c01);
    c11 = grpMinI<P>(c11);

    // All lanes hold the written-cell values -> fw for next step (m = k).
    // Identical arithmetic to writeCell => bitwise-equal values.
    const float v10f = (gB + vRc) + kArcBonus;
    const float new10 = (v10f > kThresh) ? v10f : kNeg;
    float v11m = g11;
    if (new10 > v11m) v11m = new10;
    fw11 = (v11m > kThresh) ? v11m : kNeg;  // w.y = s11(i,j)
    fw01 = (g01 > kThresh) ? g01 : kNeg;    // w.z = s01(i,j)
    fw10 = (v10f > kThresh) ? v10f : kNeg;  // w.w = s10(i,j)

    if (act && l == 0) {
        writeCell(Q4, wsBT, qjbc, i, rbi + k - 1, k,
                  gB, cB, vLc, vRc, g01, c01, g11, c11);
    }
}

// Phase driver: per-step barrier; dead waves (monotone in k) drop to a
// barrier-only loop and stop issuing the body (R8/R10-verified pattern).
template <int LP, int C>
__device__ __forceinline__ void runPhaseC(int k0, int k1, int tid,
        float4* __restrict__ Q4, uint32_t* __restrict__ wsBT,
        const float* __restrict__ v,
        float (&r11)[kCMax], float (&r01)[kCMax], float (&r10)[kCMax]) {
    const int i = tid >> LP;
    const int l = tid & ((1 << LP) - 1);
    const int firstGroup = (tid & ~63) >> LP;   // wave-uniform
    int kEnd = kN - firstGroup;                 // first k with whole wave dead
    if (kEnd > k1) kEnd = k1;
    if (kEnd > k0) {
        int j = i + k0;
        int qjb = colBaseD(j);
        const int rbi = rowBase(i & (kN - 1));  // clamped; unused when inactive
        const float* pL = v + (size_t)j * kN + i;
        const float* pR = v + (size_t)i * kN + j;
        const bool a0 = i < kN - k0;
        float vL = a0 ? *pL : 0.f;  // issue loads first: latency hides under preload
        float vR = a0 ? *pR : 0.f;
        preloadRow<LP, C>(k0, tid, Q4, r11, r01, r10);
        float fw11 = kNeg, fw01 = kNeg, fw10 = kNeg;
        fwInit<LP, C>(k0, tid, r11, r01, r10, fw11, fw01, fw10);
        for (int k = k0; k < kEnd; ++k) {
            doStepC<LP, C>(k, i, l, Q4, wsBT, j, qjb, rbi, pL, pR, vL, vR,
                           r11, r01, r10, fw11, fw01, fw10);
            ldsBarrier();
        }
        for (int k = kEnd; k < k1; ++k) ldsBarrier();
    } else {
        for (int k = k0; k < k1; ++k) ldsBarrier();
    }
}

// ---- Barrier-free single-wave tail (k = kTail..127) ----
// For k >= 112, active rows are 0..15 and any cell (q, j) with q >= 16 has
// width j - q <= 127 - 16 = 111 < 112: ALL out-of-tail dependencies are
// pre-tail (visible after the entry barrier), and every in-tail write comes
// from rows 0..15.  One wave owning rows 0..15 (P=4 lanes/row, C=32) thus
// satisfies every in-tail dependency via same-wave earlier-program-order
// ds_writes (per-wave in-order LDS, the R12-verified mechanism): zero
// barriers for 16 steps.  Row operands are read from LDS (no register cache
// -- R13's spill lesson).  Waves 1..15 wait at the single exit barrier.
__device__ __forceinline__ void runTail(int tid,
        float4* __restrict__ Q4, uint32_t* __restrict__ wsBT,
        const float* __restrict__ v) {
    if (tid < 64) {
        const int i = tid >> 2;     // group = row, 16 rows
        const int l = tid & 3;
        const int rbi = rowBase(i);
        int j = i + kTail;
        int qjb = colBaseD(j);
        const float* pL = v + (size_t)j * kN + i;
        const float* pR = v + (size_t)i * kN + j;
        float vL = *pL;             // all 16 rows active at k=112
        float vR = *pR;
        for (int k = kTail; k < kN; ++k) {
            const bool act = i < kN - k;
            const float vLc = vL, vRc = vR;
            const int qjbc = qjb;
            const int mlo = l * 32;
            const int mstart = mlo ? mlo : 1;
            const int mhi = (mlo + 32 < k) ? (mlo + 32) : k;
            float bmax = -3.0e38f, v01 = -3.0e38f, v11 = -3.0e38f;
            int ib = 0x7FFFFFFF, i01 = 0x7FFFFFFF, i11 = 0x7FFFFFFF;
            const bool lact = act && (mstart < mhi);
            if (lact) {
                int q = i + mstart;
                float4 cur = Q4[qjbc + q];   // quad(i+mstart, j)
                if (mlo == 0) {
                    bmax = cur.z; ib = 0;    // base(0) = 0 + s01[i+1][j]
                    const float p00 = (cur.z + vLc) + kArcBonus;
                    v01 = (p00 > kThresh) ? p00 : kNeg; i01 = 0;  // part00 seed
                }
                int dA = colBaseD(q) + i;    // cell (i, q)
                int dInc = q + 1;
#pragma unroll 8
                for (int m = mstart; m < mhi; ++m) {
                    const float4 nxt = Q4[qjbc + q + 1];  // quad(q+1, j)
                    const float4 diq = Q4[dA];            // quad(i, q): row operand
                    const float base = diq.y + nxt.z;     // s11[i][q] + s01[q+1][j]
                    const float p01v = diq.z + cur.x;     // s01[i][q] + s00[q][j]
                    const float p11v = diq.w + cur.y;     // s10[i][q] + s11[q][j]
                    if (base > bmax) { bmax = base; ib = m; }  // strict > keeps earliest m
                    if (p01v > v01) { v01 = p01v; i01 = m; }
                    if (p11v > v11) { v11 = p11v; i11 = m; }
                    cur = nxt;
                    dA += dInc; ++dInc; ++q;
                }
            }
            // Prefetch next step's vL/vR (overlaps reduction).
            {
                const bool nact = i < kN - (k + 1);
                qjb += j + 1; ++j; pL += kN; ++pR;
                vL = nact ? *pL : 0.f;
                vR = nact ? *pR : 0.f;
            }
            // P=4 reduction (2 DPP levels, within each quad of lanes).
            const float gB = grpMax<4>(bmax);
            const float g01 = grpMax<4>(v01);
            const float g11 = grpMax<4>(v11);
            int cB = (bmax == gB) ? ib : 0x7FFFFFFF;
            int c01 = (v01 == g01) ? i01 : 0x7FFFFFFF;
            int c11 = (v11 == g11) ? i11 : 0x7FFFFFFF;
            cB = grpMinI<4>(cB);
            c01 = grpMinI<4>(c01);
            c11 = grpMinI<4>(c11);
            if (act && l == 0) {
                writeCell(Q4, wsBT, qjbc, i, rbi + k - 1, k,
                          gB, cB, vLc, vRc, g01, c01, g11, c11);
            }
            asm volatile("" ::: "memory");  // keep step order (no instruction)
        }
    }
    // Single rendezvous: tail writes (incl. lgkmcnt drain) visible to all.
    ldsBarrier();
}

__global__ __launch_bounds__(kThreads) void eisner_dp(
    const float* __restrict__ vinfo,  // [B][N][N] fp32
    float* __restrict__ outS,         // [B][N][N][2][2] fp32 scores
    float* __restrict__ outBT,        // [B][N][N][2][2] fp32 backtrace (integer-valued)
    uint32_t* __restrict__ btPacked)  // [B][kTri] packed backtrace bytes (d_ws)
{
    extern __shared__ float4 Q4[];

    const int tid = threadIdx.x;
    const int b = blockIdx.x;
    const float* v = vinfo + (size_t)b * kN * kN;
    uint32_t* wsBT = btPacked + (size_t)b * kTri;

    // Diagonal quads = 0. Off-diagonal cells need no init (written before read).
    const float4 zeroq = make_float4(0.f, 0.f, 0.f, 0.f);
    if (tid < kN) Q4[colBaseD(tid) + tid] = zeroq;
    __syncthreads();

    // ---- barrier-free serial region (k = 1..24): waves 0..3, rows 40w+lane ----
    if (tid < 4 * 64) {
        const int w = tid >> 6;
        const int lam = tid & 63;
        const int i = kStride * w + lam;       // row (w=3 tail lanes have i>127: dead)
        const int ic = (i < kN) ? i : (kN - 1);
        float sr11[kSer + 1], sr01[kSer + 1], sr10[kSer + 1];
        int j = i + 1;
        int qjb = colBaseD((i + 1 < kN) ? i + 1 : kN - 1);  // addr-safe; dead lanes never access
        const int rbi = rowBase(ic);
        const float* pL = v + (size_t)((i + 1 < kN) ? i + 1 : 0) * kN + ic;
        const float* pR = v + (size_t)ic * kN + ((i + 1 < kN) ? i + 1 : 0);
        const bool a0 = (lam + 1 <= 63) && (i < kN - 1);
        float vL = a0 ? *pL : 0.f;
        float vR = a0 ? *pR : 0.f;
#pragma unroll
        for (int k = 1; k <= kSer; ++k) {
            doStepSerialNB(k, lam, i, Q4, wsBT, j, qjb, rbi, pL, pR, vL, vR,
                           sr11, sr01, sr10);
            asm volatile("" ::: "memory");  // program-order fence (no instruction)
        }
    }
    // Single rendezvous makes the whole k<=24 chart visible to all waves.
    ldsBarrier();

    // Row caches (registers); slots filled by preloadRow + fw commits.
    float r11[kCMax], r01[kCMax], r10[kCMax];
#pragma unroll
    for (int c = 0; c < kCMax; ++c) { r11[c] = kNeg; r01[c] = kNeg; r10[c] = kNeg; }

    // Tight phase table from k0=25 (P*C >= k1-1):
    runPhaseC<3, 5>(25, 40, tid, Q4, wsBT, v, r11, r01, r10);   // 8*5=40 >= 39
    runPhaseC<3, 7>(40, 56, tid, Q4, wsBT, v, r11, r01, r10);   // 8*7=56 >= 55
    runPhaseC<3, 9>(56, 64, tid, Q4, wsBT, v, r11, r01, r10);   // 8*9=72 >= 63
    runPhaseC<4, 5>(64, 80, tid, Q4, wsBT, v, r11, r01, r10);   // 16*5=80 >= 79
    runPhaseC<4, 7>(80, 112, tid, Q4, wsBT, v, r11, r01, r10);  // 16*7=112 >= 111

    // ---- barrier-free single-wave tail: k = 112..127 ----
    runTail(tid, Q4, wsBT, v);

    // Full barrier (drains vmcnt) before reading wsBT back.
    __syncthreads();

    // ---- epilogue: emit full [N][N][2][2] scores + backtrace, coalesced ----
    float4* gS4 = (float4*)(outS + (size_t)b * kN * kN * 4);
    float4* gB4 = (float4*)(outBT + (size_t)b * kN * kN * 4);
    const float4 negq = make_float4(kNeg, kNeg, kNeg, kNeg);
    for (int c = tid; c < kN * kN; c += kThreads) {
        const int i = c >> 7, j = c & (kN - 1);
        if (i < j) {
            const float4 q = Q4[colBaseD(j) + i];
            gS4[c] = make_float4(q.x, q.z, q.w, q.y);  // {s00, s01, s10, s11}
            const uint32_t p = wsBT[rowBase(i) + (j - i - 1)];
            gB4[c] = make_float4((float)(p & 255u), (float)((p >> 8) & 255u),
                                 (float)((p >> 16) & 255u), (float)(p >> 24));
        } else if (i == j) {
            gS4[c] = zeroq;
            gB4[c] = zeroq;
        } else {
            gS4[c] = negq;
            gB4[c] = zeroq;
        }
    }
}

extern "C" void kernel_launch(void* const* d_in, const int* in_sizes, int n_in,
                              void* d_out, int out_size, void* d_ws, size_t ws_size,
                              hipStream_t stream) {
    (void)n_in; (void)out_size; (void)ws_size;
    const float* vinfo = (const float*)d_in[0];  // fp32 [B][N][N]
    const int B = in_sizes[1];                   // b_buffer_size has B elements
    float* outS = (float*)d_out;
    float* outBT = outS + (size_t)B * kN * kN * 4;
    uint32_t* btPacked = (uint32_t*)d_ws;        // needs B*kTri*4 = ~2.1 MB

    hipFuncSetAttribute(reinterpret_cast<const void*>(eisner_dp),
                        hipFuncAttributeMaxDynamicSharedMemorySize, kDynLds);

    eisner_dp<<<dim3(B), dim3(kThreads), kDynLds, stream>>>(vinfo, outS, outBT, btPacked);
}

// Round 16
// 227.570 us; speedup vs baseline: 1.0936x; 1.0936x over previous
//
#include <hip/hip_runtime.h>
#include <stdint.h>

static constexpr int kN = 128;
static constexpr int kTri = (kN * (kN - 1)) / 2;   // 8128 (BT scratch indexing)
static constexpr int kTriD = (kN * (kN + 1)) / 2;  // 8256 cells incl. diagonal
static constexpr int kThreads = 1024;              // 16 waves: 4/SIMD TLP required (R8/R10)
static constexpr float kNeg = -9999.0f;
static constexpr float kThresh = -9000.0f;
static constexpr float kArcBonus = 5.0f;
static constexpr int kDynLds = kTriD * 16;  // 132,096 B (one float4 quad per cell)
static constexpr int kCMax = 9;             // max row-cache slots per lane
static constexpr int kSer = 24;             // barrier-free serial region: k = 1..24 (28/32 spill)

__device__ __forceinline__ int rowBase(int i) { return (i * (2 * kN - 1 - i)) / 2; }
__device__ __forceinline__ int colBaseD(int c) { return (c * (c + 1)) / 2; }  // cells (r<=c, c)

// LDS-only workgroup barrier: orders LDS without draining vmcnt (wsBT stores
// and vL/vR prefetch loads stay in flight across steps).
__device__ __forceinline__ void ldsBarrier() {
    asm volatile("s_waitcnt lgkmcnt(0)\n\ts_barrier" ::: "memory");
}

// DPP cross-lane reduce helpers -- pure VALU, never touch the LDS pipe.
// 0xB1 xor1, 0x4E xor2, 0x141 half-mirror (8 lanes), 0x140 row-mirror (16).
template <int CTRL>
__device__ __forceinline__ float dppMax(float x) {
    const int y = __builtin_amdgcn_update_dpp(__float_as_int(x), __float_as_int(x),
                                              CTRL, 0xF, 0xF, true);
    return fmaxf(x, __int_as_float(y));
}
template <int CTRL>
__device__ __forceinline__ int dppMinI(int x) {
    const int y = __builtin_amdgcn_update_dpp(x, x, CTRL, 0xF, 0xF, true);
    return (y < x) ? y : x;
}
template <int P>
__device__ __forceinline__ float grpMax(float x) {
    float r = dppMax<0xB1>(x);
    if constexpr (P >= 4) r = dppMax<0x4E>(r);
    if constexpr (P >= 8) r = dppMax<0x141>(r);
    if constexpr (P >= 16) r = dppMax<0x140>(r);
    return r;
}
template <int P>
__device__ __forceinline__ int grpMinI(int x) {
    int r = dppMinI<0xB1>(x);
    if constexpr (P >= 4) r = dppMinI<0x4E>(r);
    if constexpr (P >= 8) r = dppMinI<0x141>(r);
    if constexpr (P >= 16) r = dppMinI<0x140>(r);
    return r;
}

// Quad per cell: {x=s00, y=s11, z=s01, w=s10}, col-major incl. diagonal (diag=0).
__device__ __forceinline__ float4 writeCell(float4* __restrict__ Q4,
                                            uint32_t* __restrict__ wsBT,
                                            int qjb, int i, int wsIdx, int k,
                                            float gb, int ib, float vLc, float vRc,
                                            float v01, int i01, float v11, int i11) {
    const float v00 = (gb + vLc) + kArcBonus;
    const float v10 = (gb + vRc) + kArcBonus;
    const float new10 = (v10 > kThresh) ? v10 : kNeg;
    if (new10 > v11) { v11 = new10; i11 = k; }  // q=j candidate; strict > keeps earlier q
    float4 w = make_float4(kNeg, kNeg, kNeg, kNeg);
    uint32_t p = 0;
    if (v00 > kThresh) { w.x = v00; p |= (uint32_t)(i + ib); }
    if (v01 > kThresh) { w.z = v01; p |= (uint32_t)(i + i01) << 8; }
    if (v10 > kThresh) { w.w = v10; p |= (uint32_t)(i + ib) << 16; }
    if (v11 > kThresh) { w.y = v11; p |= (uint32_t)(i + i11) << 24; }
    Q4[qjb + i] = w;      // one ds_write_b128
    wsBT[wsIdx] = p;      // lone global store; drained at the final __syncthreads
    return w;
}

// ---- Barrier-free serial region (k = 1..kSer) ----
// Waves 0..3 own rows r = 40*w + lane.  A lane runs step k only while
// lam + k <= 63; then every cell (q, r+k) it reads has writer-lane
// lam_q = lam + (q - r) with lam_q + width = lam + k <= 63 -- SAME WAVE,
// earlier step.  Per-wave in-order LDS => visible without any barrier.  Rows
// covered twice (lam >= 40 duplicates wave w+1's primaries) are computed
// bitwise-identically (same inputs, same code) => benign same-value writes,
// incl. wsBT.  Primaries (lam < 40) stay valid through k = 24, covering
// every row 0..127.
// REGISTER BUDGET (R13/R14 lesson): live sr ~= 3*(k-1); kSer=24 fits the
// 128-VGPR cap at 4 waves/SIMD; kSer=28/32 spill to scratch.
__device__ __forceinline__ void doStepSerialNB(int k, int lam, int i,
                                               float4* __restrict__ Q4,
                                               uint32_t* __restrict__ wsBT,
                                               int& j, int& qjb, int rbi,
                                               const float*& pL, const float*& pR,
                                               float& vL, float& vR,
                                               float (&sr11)[kSer + 1], float (&sr01)[kSer + 1],
                                               float (&sr10)[kSer + 1]) {
    const bool act = (lam + k <= 63) && (i < kN - k);
    const float vLc = vL, vRc = vR;
    const int qjbc = qjb;
    float bmax = -3.0e38f, v01 = -3.0e38f, v11 = -3.0e38f;
    int ib = 0, i01 = 0, i11 = 0x7FFFFFFF;
    if (act) {
        float4 cur = Q4[qjbc + i + 1];  // quad(i+1, j); diagonal zeros when k==1
        bmax = cur.z; ib = 0;           // base(0) = 0 + s01[i+1][j]
        const float p00 = (cur.z + vLc) + kArcBonus;
        v01 = (p00 > kThresh) ? p00 : kNeg; i01 = 0;  // part00 seed
#pragma unroll
        for (int m = 1; m < kSer; ++m) {
            if (m < k) {  // compile-time when k is constant-folded
                const float4 nxt = Q4[qjbc + i + m + 1];  // quad(q+1, j)
                const float base = sr11[m] + nxt.z;       // s11[i][q] + s01[q+1][j]
                const float p01v = sr01[m] + cur.x;       // s01[i][q] + s00[q][j]
                const float p11v = sr10[m] + cur.y;       // s10[i][q] + s11[q][j]
                if (base > bmax) { bmax = base; ib = m; }  // strict > keeps earliest m
                if (p01v > v01) { v01 = p01v; i01 = m; }
                if (p11v > v11) { v11 = p11v; i11 = m; }
                cur = nxt;
            }
        }
    }
    // Incremental prefetch of next step's operands (overlaps write).
    if (k < kSer) {
        const bool nact = (lam + k + 1 <= 63) && (i < kN - (k + 1));
        qjb += j + 1; ++j; pL += kN; ++pR;
        vL = nact ? *pL : 0.f;
        vR = nact ? *pR : 0.f;
    }
    if (act) {
        const float4 w = writeCell(Q4, wsBT, qjbc, i, rbi + k - 1, k,
                                   bmax, ib, vLc, vRc, v01, i01, v11, i11);
        sr11[k] = w.y; sr01[k] = w.z; sr10[k] = w.w;  // constant index (k unrolled)
    }
}

// ---- Chunked phases: register row-cache + fw forwarding (R7, verified) ----
template <int LP, int C>
__device__ __forceinline__ void preloadRow(int k0, int tid,
                                           const float4* __restrict__ Q4,
                                           float (&r11)[kCMax], float (&r01)[kCMax],
                                           float (&r10)[kCMax]) {
    const int i = tid >> LP;
    const int l = tid & ((1 << LP) - 1);
    const int mlo = l * C;
    const int mstart = mlo ? mlo : 1;
    const bool act = i < (kN - k0);
#pragma unroll
    for (int c = 0; c < C; ++c) {
        const int m = mstart + c;
        if (act && (m < mlo + C) && (m <= k0 - 1)) {
            const float4 d = Q4[colBaseD(i + m) + i];  // quad(i, i+m), immutable
            r11[c] = d.y; r01[c] = d.z; r10[c] = d.w;
        }
    }
    // Slots with m > k0-1 stay stale: first read at step k=m+1 substitutes fw.
}

template <int LP, int C>
__device__ __forceinline__ void fwInit(int k0, int tid,
                                       const float (&r11)[kCMax], const float (&r01)[kCMax],
                                       const float (&r10)[kCMax],
                                       float& fw11, float& fw01, float& fw10) {
    const int l = tid & ((1 << LP) - 1);
    const int mlo = l * C;
    const int mstart = mlo ? mlo : 1;
#pragma unroll
    for (int c = 0; c < C; ++c) {
        if (mstart + c == k0 - 1) { fw11 = r11[c]; fw01 = r01[c]; fw10 = r10[c]; }
    }
}

template <int LP, int C>
__device__ __forceinline__ void doStepC(int k, int i, int l,
                                        float4* __restrict__ Q4,
                                        uint32_t* __restrict__ wsBT,
                                        int& j, int& qjb, int rbi,
                                        const float*& pL, const float*& pR,
                                        float& vL, float& vR,
                                        float (&r11)[kCMax], float (&r01)[kCMax],
                                        float (&r10)[kCMax],
                                        float& fw11, float& fw01, float& fw10) {
    constexpr int P = 1 << LP;
    static_assert(P <= 16, "reductions must stay pure-DPP");
    const bool act = i < kN - k;
    const float vLc = vL, vRc = vR;  // prefetch below overwrites vL/vR
    const int mlo = l * C;
    const int mstart = mlo ? mlo : 1;
    const int mhi = (mlo + C < k) ? (mlo + C) : k;
    const int qjbc = qjb;

    float bmax = -3.0e38f, v01 = -3.0e38f, v11 = -3.0e38f;
    int ib = 0x7FFFFFFF, i01 = 0x7FFFFFFF, i11 = 0x7FFFFFFF;

    const int mf = k - 1;
    const bool lact = act && (mstart < mhi);
    float4 cur = make_float4(0.f, 0.f, 0.f, 0.f);
    if (lact) cur = Q4[qjbc + i + mstart];  // column seed quad(i+mstart, j)
    if (act && mlo == 0) {
        bmax = cur.z; ib = 0;  // base(0) = 0 + s01[i+1][j]
        const float p00 = (cur.z + vLc) + kArcBonus;
        v01 = (p00 > kThresh) ? p00 : kNeg; i01 = 0;  // part00 seed
    }
#pragma unroll
    for (int c = 0; c < C; ++c) {
        const int m = mstart + c;
        // Row operands: registers; fresh slot m==k-1 comes from fw (the cell
        // this group computed last step), committed into the cache here.
        const bool isF = (m == mf);
        const float a11 = isF ? fw11 : r11[c];
        const float a01 = isF ? fw01 : r01[c];
        const float a10 = isF ? fw10 : r10[c];
        r11[c] = a11; r01[c] = a01; r10[c] = a10;
        const bool on = lact && (m < mhi);
        if (on) {
            const float4 nxt = Q4[qjbc + i + m + 1];  // quad(q+1, j); imm offset
            const float base = a11 + nxt.z;           // s11[i][q] + s01[q+1][j]
            const float p01v = a01 + cur.x;           // s01[i][q] + s00[q][j]
            const float p11v = a10 + cur.y;           // s10[i][q] + s11[q][j]
            if (base > bmax) { bmax = base; ib = m; }  // strict > keeps earliest m
            if (p01v > v01) { v01 = p01v; i01 = m; }
            if (p11v > v11) { v11 = p11v; i11 = m; }
            cur = nxt;
        }
    }

    // Incremental prefetch of next step's operands (overlaps reduction+barrier).
    {
        const bool nact = i < kN - (k + 1);
        qjb += j + 1; ++j; pL += kN; ++pR;
        vL = nact ? *pL : 0.f;
        vR = nact ? *pR : 0.f;
    }

    // Value butterfly (pure DPP, VALU pipe only): log2(P) levels.
    const float gB = grpMax<P>(bmax);
    const float g01 = grpMax<P>(v01);
    const float g11 = grpMax<P>(v11);
    // Earliest-m argmax: mask losers to INT_MAX, min-butterfly (pure DPP).
    int cB = (bmax == gB) ? ib : 0x7FFFFFFF;
    int c01 = (v01 == g01) ? i01 : 0x7FFFFFFF;
    int c11 = (v11 == g11) ? i11 : 0x7FFFFFFF;
    cB = grpMinI<P>(cB);
    c01 = grpMinI<P>(c01);
    c11 = grpMinI<P>(c11);

    // All lanes hold the written-cell values -> fw for next step (m = k).
    // Identical arithmetic to writeCell => bitwise-equal values.
    const float v10f = (gB + vRc) + kArcBonus;
    const float new10 = (v10f > kThresh) ? v10f : kNeg;
    float v11m = g11;
    if (new10 > v11m) v11m = new10;
    fw11 = (v11m > kThresh) ? v11m : kNeg;  // w.y = s11(i,j)
    fw01 = (g01 > kThresh) ? g01 : kNeg;    // w.z = s01(i,j)
    fw10 = (v10f > kThresh) ? v10f : kNeg;  // w.w = s10(i,j)

    if (act && l == 0) {
        writeCell(Q4, wsBT, qjbc, i, rbi + k - 1, k,
                  gB, cB, vLc, vRc, g01, c01, g11, c11);
    }
}

// Phase driver: barrier per step (R7 structure), incremental addressing.
template <int LP, int C>
__device__ __forceinline__ void runPhaseC(int k0, int k1, int tid,
        float4* __restrict__ Q4, uint32_t* __restrict__ wsBT,
        const float* __restrict__ v,
        float (&r11)[kCMax], float (&r01)[kCMax], float (&r10)[kCMax]) {
    const int i = tid >> LP;
    const int l = tid & ((1 << LP) - 1);
    int j = i + k0;
    int qjb = colBaseD(j);
    const int rbi = rowBase(i & (kN - 1));  // clamped; unused when inactive
    const float* pL = v + (size_t)j * kN + i;
    const float* pR = v + (size_t)i * kN + j;
    const bool a0 = i < kN - k0;
    float vL = a0 ? *pL : 0.f;  // issue loads first: latency hides under preload
    float vR = a0 ? *pR : 0.f;
    preloadRow<LP, C>(k0, tid, Q4, r11, r01, r10);
    float fw11 = kNeg, fw01 = kNeg, fw10 = kNeg;
    fwInit<LP, C>(k0, tid, r11, r01, r10, fw11, fw01, fw10);
    for (int k = k0; k < k1; ++k) {
        doStepC<LP, C>(k, i, l, Q4, wsBT, j, qjb, rbi, pL, pR, vL, vR,
                       r11, r01, r10, fw11, fw01, fw10);
        ldsBarrier();
    }
}

__global__ __launch_bounds__(kThreads) void eisner_dp(
    const float* __restrict__ vinfo,  // [B][N][N] fp32
    float* __restrict__ outS,         // [B][N][N][2][2] fp32 scores
    float* __restrict__ outBT,        // [B][N][N][2][2] fp32 backtrace (integer-valued)
    uint32_t* __restrict__ btPacked)  // [B][kTri] packed backtrace bytes (d_ws)
{
    extern __shared__ float4 Q4[];

    const int tid = threadIdx.x;
    const int b = blockIdx.x;
    const float* v = vinfo + (size_t)b * kN * kN;
    uint32_t* wsBT = btPacked + (size_t)b * kTri;

    // Diagonal quads = 0. Off-diagonal cells need no init (written before read).
    const float4 zeroq = make_float4(0.f, 0.f, 0.f, 0.f);
    if (tid < kN) Q4[colBaseD(tid) + tid] = zeroq;
    __syncthreads();

    // ---- barrier-free serial region (k = 1..24): waves 0..3, rows 40w+lane ----
    if (tid < 4 * 64) {
        const int w = tid >> 6;
        const int lam = tid & 63;
        const int i = 40 * w + lam;            // row (w=3 tail lanes have i>127: dead)
        const int ic = (i < kN) ? i : (kN - 1);
        float sr11[kSer + 1], sr01[kSer + 1], sr10[kSer + 1];
        int j = i + 1;
        int qjb = colBaseD((i + 1 < kN) ? i + 1 : kN - 1);  // addr-safe; dead lanes never access
        const int rbi = rowBase(ic);
        const float* pL = v + (size_t)((i + 1 < kN) ? i + 1 : 0) * kN + ic;
        const float* pR = v + (size_t)ic * kN + ((i + 1 < kN) ? i + 1 : 0);
        const bool a0 = (lam + 1 <= 63) && (i < kN - 1);
        float vL = a0 ? *pL : 0.f;
        float vR = a0 ? *pR : 0.f;
#pragma unroll
        for (int k = 1; k <= kSer; ++k) {
            doStepSerialNB(k, lam, i, Q4, wsBT, j, qjb, rbi, pL, pR, vL, vR,
                           sr11, sr01, sr10);
            asm volatile("" ::: "memory");  // program-order fence (no instruction)
        }
    }
    // Single rendezvous makes the whole k<=24 chart visible to all waves.
    ldsBarrier();

    // Row caches (registers); slots filled by preloadRow + fw commits.
    float r11[kCMax], r01[kCMax], r10[kCMax];
#pragma unroll
    for (int c = 0; c < kCMax; ++c) { r11[c] = kNeg; r01[c] = kNeg; r10[c] = kNeg; }

    // Tight phase table from k0=25 (P*C >= k1-1):
    runPhaseC<3, 5>(25, 40, tid, Q4, wsBT, v, r11, r01, r10);   // 8*5=40 >= 39
    runPhaseC<3, 7>(40, 56, tid, Q4, wsBT, v, r11, r01, r10);   // 8*7=56 >= 55
    runPhaseC<3, 9>(56, 64, tid, Q4, wsBT, v, r11, r01, r10);   // 8*9=72 >= 63
    runPhaseC<4, 5>(64, 80, tid, Q4, wsBT, v, r11, r01, r10);   // 16*5=80 >= 79
    runPhaseC<4, 7>(80, 112, tid, Q4, wsBT, v, r11, r01, r10);  // 16*7=112 >= 111
    runPhaseC<4, 9>(112, 128, tid, Q4, wsBT, v, r11, r01, r10); // 16*9=144 >= 127

    // Full barrier (drains vmcnt) before reading wsBT back.
    __syncthreads();

    // ---- epilogue: emit full [N][N][2][2] scores + backtrace, coalesced ----
    float4* gS4 = (float4*)(outS + (size_t)b * kN * kN * 4);
    float4* gB4 = (float4*)(outBT + (size_t)b * kN * kN * 4);
    const float4 negq = make_float4(kNeg, kNeg, kNeg, kNeg);
    for (int c = tid; c < kN * kN; c += kThreads) {
        const int i = c >> 7, j = c & (kN - 1);
        if (i < j) {
            const float4 q = Q4[colBaseD(j) + i];
            gS4[c] = make_float4(q.x, q.z, q.w, q.y);  // {s00, s01, s10, s11}
            const uint32_t p = wsBT[rowBase(i) + (j - i - 1)];
            gB4[c] = make_float4((float)(p & 255u), (float)((p >> 8) & 255u),
                                 (float)((p >> 16) & 255u), (float)(p >> 24));
        } else if (i == j) {
            gS4[c] = zeroq;
            gB4[c] = zeroq;
        } else {
            gS4[c] = negq;
            gB4[c] = zeroq;
        }
    }
}

extern "C" void kernel_launch(void* const* d_in, const int* in_sizes, int n_in,
                              void* d_out, int out_size, void* d_ws, size_t ws_size,
                              hipStream_t stream) {
    (void)n_in; (void)out_size; (void)ws_size;
    const float* vinfo = (const float*)d_in[0];  // fp32 [B][N][N]
    const int B = in_sizes[1];                   // b_buffer_size has B elements
    float* outS = (float*)d_out;
    float* outBT = outS + (size_t)B * kN * kN * 4;
    uint32_t* btPacked = (uint32_t*)d_ws;        // needs B*kTri*4 = ~2.1 MB

    hipFuncSetAttribute(reinterpret_cast<const void*>(eisner_dp),
                        hipFuncAttributeMaxDynamicSharedMemorySize, kDynLds);

    eisner_dp<<<dim3(B), dim3(kThreads), kDynLds, stream>>>(vinfo, outS, outBT, btPacked);
}